// Round 18
// baseline (1452.068 us; speedup 1.0000x reference)
//
#include <hip/hip_runtime.h>
#include <math.h>

#define Bz 64
#define Tz 12000
#define Pz 50
#define Dz 200
#define Lz 12
#define Hz 10
#define HDz 20
#define FFz 800
#define Nz 240
#define Sz 241
#define Sp 256                // padded seq stride
#define NRDz 482
#define NCz 1000
#define BS (Bz * Sz)          // 15424 valid rows
#define Mp (Bz * Sp)          // 16384 padded rows
#define Kp 224                // K=200 padded to 7*32
#define PEM (Bz * Nz)         // 15360 patch rows
#define SCALEq 0.22360679774997896f
#define LOG2E 1.4426950408889634f
#define SCALE2f (SCALEq * LOG2E)
#define BIASL 655360          // shorts per layer of bias table

typedef __attribute__((ext_vector_type(8))) short bf16x8;
typedef __attribute__((ext_vector_type(4))) float f32x4;

static __device__ __forceinline__ short f2b(float f) {
    unsigned u = __float_as_uint(f);
    unsigned r = (u + 0x7fffu + ((u >> 16) & 1u)) >> 16;
    return (short)r;
}
static __device__ __forceinline__ float b2f(short v) {
    return __uint_as_float(((unsigned)(unsigned short)v) << 16);
}
static __device__ __forceinline__ uint2 pk4(float a, float b, float c, float d) {
    uint2 r;
    asm("v_cvt_pk_bf16_f32 %0, %1, %2" : "=v"(r.x) : "v"(a), "v"(b));
    asm("v_cvt_pk_bf16_f32 %0, %1, %2" : "=v"(r.y) : "v"(c), "v"(d));
    return r;
}
static __device__ __forceinline__ float frcp(float x) {
    float r;
    asm("v_rcp_f32 %0, %1" : "=v"(r) : "v"(x));
    return r;
}
static __device__ __forceinline__ float gelu_f(float v) {
    float u = v * (0.7978845608f + 0.03567740814f * v * v);
    float e = exp2f(2.885390082f * u);
    return v * e * frcp(e + 1.f);
}
static __device__ __forceinline__ void gll16(const void* g, void* l) {
    __builtin_amdgcn_global_load_lds((const __attribute__((address_space(1))) unsigned*)g,
                                     (__attribute__((address_space(3))) unsigned*)l, 16, 0, 0);
}
template <int N> static __device__ __forceinline__ void wait_vm() {
    if constexpr (N == 0) asm volatile("s_waitcnt vmcnt(0)" ::: "memory");
    else if constexpr (N == 1) asm volatile("s_waitcnt vmcnt(1)" ::: "memory");
    else if constexpr (N == 2) asm volatile("s_waitcnt vmcnt(2)" ::: "memory");
    else if constexpr (N == 3) asm volatile("s_waitcnt vmcnt(3)" ::: "memory");
    else if constexpr (N == 4) asm volatile("s_waitcnt vmcnt(4)" ::: "memory");
    else if constexpr (N == 5) asm volatile("s_waitcnt vmcnt(5)" ::: "memory");
    else if constexpr (N == 6) asm volatile("s_waitcnt vmcnt(6)" ::: "memory");
}

// ---------------- f32 [L][N][K] -> bf16 [L][Npad][Kpad] zero-padded ----------------
__global__ void cvt_pad_k(const float* __restrict__ in, short* __restrict__ out,
                          int N, int K, int Npad, int Kpad, int total) {
    int i = blockIdx.x * 256 + threadIdx.x;
    if (i >= total) return;
    int pk = Npad * Kpad;
    int l = i / pk;
    int r = i - l * pk;
    int n = r / Kpad;
    int k = r - n * Kpad;
    float v = (n < N && k < K) ? in[((size_t)l * N + n) * K + k] : 0.f;
    out[i] = f2b(v);
}

// ---------------- x -> bf16 patches [15360][64] ----------------
__global__ void xcvt_k(const float* __restrict__ x, short* __restrict__ xb) {
    int i = blockIdx.x * 256 + threadIdx.x;
    int m = i >> 6, k = i & 63;
    int b = m / Nz, j = m - b * Nz;
    xb[i] = (k < Pz) ? f2b(x[(size_t)b * Tz + j * Pz + k]) : 0;
}

// ---------------- cls rows ----------------
__global__ void cls_k(const float* __restrict__ cls, const float* __restrict__ pos,
                      float* __restrict__ tok) {
    int b = blockIdx.x, d = threadIdx.x;
    if (d < Dz) tok[(size_t)b * Sp * Dz + d] = cls[d] + pos[d];
}

// ---------------- layernorm v2 (vectorized): f32 (ld 200) -> bf16 (ld 224) ----------
__global__ void ln_k(const float* __restrict__ in, short* __restrict__ out,
                     const float* __restrict__ sc, const float* __restrict__ bi) {
    int wave = threadIdx.x >> 6, lane = threadIdx.x & 63;
    int row = blockIdx.x * 4 + wave;
    if ((row & 255) >= Sz) return;
    const float* x = in + (size_t)row * Dz;
    f32x4 v = {0.f, 0.f, 0.f, 0.f};
    if (lane < 50) v = *(const f32x4*)(x + lane * 4);
    float sum = v[0] + v[1] + v[2] + v[3];
    #pragma unroll
    for (int off = 32; off; off >>= 1) sum += __shfl_xor(sum, off);
    float mean = sum * (1.f / Dz);
    float var = 0.f;
    if (lane < 50) {
        #pragma unroll
        for (int i = 0; i < 4; ++i) { float d = v[i] - mean; var += d * d; }
    }
    #pragma unroll
    for (int off = 32; off; off >>= 1) var += __shfl_xor(var, off);
    float rstd = rsqrtf(var * (1.f / Dz) + 1e-6f);
    short* o = out + (size_t)row * Kp;
    if (lane < 50) {
        f32x4 s4 = *(const f32x4*)(sc + lane * 4);
        f32x4 b4 = *(const f32x4*)(bi + lane * 4);
        short4 o4;
        #pragma unroll
        for (int r = 0; r < 4; ++r)
            ((short*)&o4)[r] = f2b((v[r] - mean) * rstd * s4[r] + b4[r]);
        *(short4*)(o + lane * 4) = o4;
    } else if (lane < 56) {
        short4 z = {0, 0, 0, 0};
        *(short4*)(o + lane * 4) = z;
    }
}

// ---------------- bias precompute v5 (merged q-halves order) ----------------
// short4 idx = lane + 64*mi + 256*w + 1024*nj + 4096*kc + 16384*h (+ layer*163840)
// q = w*64 + mi*16 + (lane&15);  k = kc*64 + nj*16 + 4*(lane>>4) + r
__global__ void bias_pre5_k(const float* __restrict__ tabs, short* __restrict__ bp) {
    int l = blockIdx.y;
    int tid = blockIdx.x * 256 + threadIdx.x;      // 163840 per layer
    const float* tab = tabs + (size_t)l * NRDz * Hz;
    int lane = tid & 63;
    int mi = (tid >> 6) & 3;
    int w  = (tid >> 8) & 3;
    int nj = (tid >> 10) & 3;
    int kc = (tid >> 12) & 3;
    int h  = tid >> 14;
    int q  = w * 64 + mi * 16 + (lane & 15);
    int k0 = kc * 64 + nj * 16 + 4 * (lane >> 4);
    short4 o;
    #pragma unroll
    for (int r = 0; r < 4; ++r) {
        int k = k0 + r;
        float v;
        if (q > Nz || k > Nz) v = -1e30f;
        else if (k == 0)      v = (q == 0) ? tab[481 * Hz + h] : tab[480 * Hz + h];
        else if (q == 0)      v = tab[479 * Hz + h];
        else                  v = tab[(q - k + 239) * Hz + h];
        ((short*)&o)[r] = f2b(v * LOG2E);
    }
    *(short4*)(bp + (size_t)l * BIASL + (size_t)tid * 4) = o;
}

// ---------------- MFMA GEMM v8 (unchanged from r17) ----------
template <int MODE, int BN2, int BM2>
__global__ __launch_bounds__(256) void gemm8_k(
        const short* __restrict__ A, const short* __restrict__ W,
        const float* __restrict__ bias, const float* __restrict__ bias2,
        const float* __restrict__ res, void* __restrict__ outv,
        short* __restrict__ qo, short* __restrict__ ko, short* __restrict__ vo,
        int M, int Nreal, int K, int strideA, int ldo, int gridx, int gridy) {
    constexpr int NJ = BN2 / 32;
    constexpr int MI = BM2 / 32;
    constexpr int AISS = BM2 / 64;
    constexpr int BISS = BN2 / 64;
    constexpr int LPS = AISS + BISS;
    __shared__ short smem[3 * (BM2 + BN2) * 32];
    short* Asb = smem;
    short* Bsb = smem + 3 * BM2 * 32;
    const int t = threadIdx.x;
    const int lane = t & 63, w = t >> 6;
    const int l15 = lane & 15, lg = lane >> 4;
    const int wm = w & 1, wn = w >> 1;

    int bx, by;
    {
        int wg = blockIdx.x;
        if ((gridy & 7) == 0) {
            int xcd = wg & 7, j = wg >> 3;
            bx = j % gridx;
            by = (j / gridx) * 8 + xcd;
        } else {
            bx = wg % gridx;
            by = wg / gridx;
        }
    }
    const int row0 = by * BM2, col0 = bx * BN2;
    const int xsw = (l15 >> 1) & 3;

    f32x4 acc[MI][NJ];
    #pragma unroll
    for (int mi = 0; mi < MI; ++mi)
        #pragma unroll
        for (int nj = 0; nj < NJ; ++nj) {
            f32x4 z = {0.f, 0.f, 0.f, 0.f};
            acc[mi][nj] = z;
        }

    const int nk = K >> 5;

    auto stage = [&](int buf, int kt) {
        const int k0 = kt * 32;
        #pragma unroll
        for (int i = 0; i < AISS; ++i) {
            int c = (w * AISS + i) * 64 + lane;
            int r = c >> 2, q = c & 3;
            const short* gp = A + (size_t)(row0 + r) * strideA + k0 + ((q ^ ((r >> 1) & 3)) * 8);
            gll16(gp, Asb + buf * BM2 * 32 + (w * AISS + i) * 512);
        }
        #pragma unroll
        for (int i = 0; i < BISS; ++i) {
            int c = (w * BISS + i) * 64 + lane;
            int r = c >> 2, q = c & 3;
            const short* gp = W + (size_t)(col0 + r) * K + k0 + ((q ^ ((r >> 1) & 3)) * 8);
            gll16(gp, Bsb + buf * BN2 * 32 + (w * BISS + i) * 512);
        }
    };

    stage(0, 0);
    if (nk > 1) stage(1, 1);
    for (int kt = 0; kt < nk; ++kt) {
        const int cur = kt % 3;
        if (kt + 1 < nk) wait_vm<LPS>();
        else             wait_vm<0>();
        __builtin_amdgcn_s_barrier();
        if (kt + 2 < nk) stage((kt + 2) % 3, kt + 2);
        bf16x8 bfr[NJ], afr[MI];
        #pragma unroll
        for (int nj = 0; nj < NJ; ++nj)
            bfr[nj] = *(const bf16x8*)(Bsb + cur * BN2 * 32 + (wn * (BN2 / 2) + nj * 16 + l15) * 32 + ((lg ^ xsw) * 8));
        #pragma unroll
        for (int mi = 0; mi < MI; ++mi)
            afr[mi] = *(const bf16x8*)(Asb + cur * BM2 * 32 + (wm * (BM2 / 2) + mi * 16 + l15) * 32 + ((lg ^ xsw) * 8));
        #pragma unroll
        for (int mi = 0; mi < MI; ++mi)
            #pragma unroll
            for (int nj = 0; nj < NJ; ++nj) {
                if (MODE == 1)
                    acc[mi][nj] = __builtin_amdgcn_mfma_f32_16x16x32_bf16(bfr[nj], afr[mi], acc[mi][nj], 0, 0, 0);
                else
                    acc[mi][nj] = __builtin_amdgcn_mfma_f32_16x16x32_bf16(afr[mi], bfr[nj], acc[mi][nj], 0, 0, 0);
            }
    }

    if (MODE == 1) {
        #pragma unroll
        for (int mi = 0; mi < MI; ++mi) {
            int m = row0 + wm * (BM2 / 2) + mi * 16 + l15;
            int b = m >> 8, s = m & 255;
            #pragma unroll
            for (int nj = 0; nj < NJ; ++nj) {
                int n0 = col0 + wn * (BN2 / 2) + nj * 16 + 4 * lg;
                if (n0 >= 600) continue;
                int which = n0 >= 400 ? 2 : (n0 >= 200 ? 1 : 0);
                int hd = n0 - which * 200;
                int h = hd / 20, d0 = hd - h * 20;
                size_t base = (size_t)(b * Hz + h) * 8192;
                if (which == 0) {
                    f32x4 qb4 = *(const f32x4*)(bias + hd);
                    short4 o4;
                    #pragma unroll
                    for (int r = 0; r < 4; ++r)
                        ((short*)&o4)[r] = f2b((acc[mi][nj][r] + qb4[r]) * SCALE2f);
                    *(short4*)(qo + base + s * 32 + d0) = o4;
                } else if (which == 1) {
                    int oct = (d0 >> 3) ^ ((s >> 1) & 3);
                    short4 o4;
                    #pragma unroll
                    for (int r = 0; r < 4; ++r)
                        ((short*)&o4)[r] = f2b(acc[mi][nj][r]);
                    *(short4*)(ko + base + s * 32 + oct * 8 + (d0 & 7)) = o4;
                } else {
                    f32x4 vb4 = *(const f32x4*)(bias2 + hd);
                    #pragma unroll
                    for (int r = 0; r < 4; ++r) {
                        int d = d0 + r;
                        vo[base + d * 256 + (s ^ ((d & 7) << 3))] = f2b(acc[mi][nj][r] + vb4[r]);
                    }
                }
            }
        }
        return;
    }

    if (MODE == 2 || MODE == 3) {
        __syncthreads();
        if (MODE == 3) {
            constexpr int EW = BN2 + 8;
            short* ep = smem;
            #pragma unroll
            for (int mi = 0; mi < MI; ++mi)
                #pragma unroll
                for (int nj = 0; nj < NJ; ++nj) {
                    int nl = wn * (BN2 / 2) + nj * 16 + l15;
                    int n = col0 + nl;
                    float bv = (n < Nreal) ? bias[n] : 0.f;
                    #pragma unroll
                    for (int r = 0; r < 4; ++r)
                        ep[(wm * (BM2 / 2) + mi * 16 + 4 * lg + r) * EW + nl] =
                            f2b(gelu_f(acc[mi][nj][r] + bv));
                }
            __syncthreads();
            constexpr int TPR = BN2 / 8;
            constexpr int RPP = 256 / TPR;
            int rowp = t / TPR, cch = t % TPR;
            #pragma unroll
            for (int p = 0; p < BM2 / RPP; ++p) {
                int row = p * RPP + rowp;
                int n = col0 + cch * 8;
                if (n + 8 <= Nreal)
                    *(bf16x8*)((short*)outv + (size_t)(row0 + row) * ldo + n) =
                        *(const bf16x8*)(ep + row * EW + cch * 8);
            }
        } else {
            constexpr int EWF = BN2 + 4;
            float* epf = (float*)smem;
            #pragma unroll
            for (int mi = 0; mi < MI; ++mi)
                #pragma unroll
                for (int nj = 0; nj < NJ; ++nj) {
                    int nl = wn * (BN2 / 2) + nj * 16 + l15;
                    int n = col0 + nl;
                    float bv = (n < Nreal) ? bias[n] : 0.f;
                    #pragma unroll
                    for (int r = 0; r < 4; ++r)
                        epf[(wm * (BM2 / 2) + mi * 16 + 4 * lg + r) * EWF + nl] =
                            acc[mi][nj][r] + bv;
                }
            __syncthreads();
            constexpr int TPR = BN2 / 4;
            constexpr int RPP = 256 / TPR;
            int rowp = t / TPR, cch = t % TPR;
            #pragma unroll
            for (int p = 0; p < BM2 / RPP; ++p) {
                int row = p * RPP + rowp;
                int n = col0 + cch * 4;
                if (n + 4 <= Nreal) {
                    size_t off = (size_t)(row0 + row) * ldo + n;
                    f32x4 v = *(const f32x4*)(epf + row * EWF + cch * 4);
                    f32x4 rr = *(const f32x4*)(res + off);
                    *(f32x4*)((float*)outv + off) = v + rr;
                }
            }
        }
        return;
    }

    #pragma unroll
    for (int mi = 0; mi < MI; ++mi) {
        #pragma unroll
        for (int nj = 0; nj < NJ; ++nj) {
            int n = col0 + wn * (BN2 / 2) + nj * 16 + l15;
            if (n >= Nreal) continue;
            if (MODE == 4) {
                #pragma unroll
                for (int r = 0; r < 4; ++r) {
                    int m = row0 + wm * (BM2 / 2) + mi * 16 + 4 * lg + r;
                    int bb = m / Nz, j = m - bb * Nz;
                    size_t trow = (size_t)bb * Sp + j + 1;
                    ((float*)outv)[trow * ldo + n] =
                        acc[mi][nj][r] + bias[n] + res[(size_t)(j + 1) * Dz + n];
                }
            } else {
                #pragma unroll
                for (int r = 0; r < 4; ++r) {
                    int m = row0 + wm * (BM2 / 2) + mi * 16 + 4 * lg + r;
                    if (m >= M) continue;
                    size_t off = (size_t)m * ldo + n;
                    ((float*)outv)[off] = acc[mi][nj][r] + bias[n];
                }
            }
        }
    }
}

// ---------------- MFMA attention v6: merged q-halves (one K/V staging per bh) -------
// 640 blocks; 4 waves x 64 q-rows each; Pl reused across the two mi-pairs.
#define PLD 72
__global__ __launch_bounds__(256) void attn6_k(const short* __restrict__ Qb,
                                               const short* __restrict__ Kb,
                                               const short* __restrict__ Vtb,
                                               const short* __restrict__ biasC,
                                               short* __restrict__ o) {
    const int bh = blockIdx.x;
    const int b = bh / Hz, h = bh - b * Hz;
    __shared__ short Ks[8192];
    __shared__ short Vt[8192];
    __shared__ short Pl[4][32 * PLD];
    const int t = threadIdx.x;
    const int lane = t & 63, w = t >> 6;
    const int l15 = lane & 15, lg = lane >> 4;

    const short* kbh = Kb + (size_t)bh * 8192;
    const short* vbh = Vtb + (size_t)bh * 8192;
    #pragma unroll
    for (int i = 0; i < 4; ++i) {
        int j = w * 4 + i;
        gll16(kbh + (size_t)(j * 64 + lane) * 8, Ks + j * 512);
        gll16(vbh + (size_t)(j * 64 + lane) * 8, Vt + j * 512);
    }
    bf16x8 qfrag[4];
    const short* qbh = Qb + (size_t)bh * 8192;
    #pragma unroll
    for (int mi = 0; mi < 4; ++mi) {
        int qrow = w * 64 + mi * 16 + l15;
        qfrag[mi] = *(const bf16x8*)(qbh + qrow * 32 + lg * 8);
    }
    const short* bpp = biasC + 4 * (size_t)(lane + 256 * w + 16384 * h);
    __syncthreads();

    f32x4 O[4][2];
    float mrow[4] = {-1e30f, -1e30f, -1e30f, -1e30f};
    float lrow[4] = {0.f, 0.f, 0.f, 0.f};
    {
        f32x4 z = {0.f, 0.f, 0.f, 0.f};
        #pragma unroll
        for (int mi = 0; mi < 4; ++mi) { O[mi][0] = z; O[mi][1] = z; }
    }
    const int xsw = (l15 >> 1) & 3;

    #pragma unroll 1
    for (int kc = 0; kc < 4; ++kc) {
        bf16x8 kf[4];
        #pragma unroll
        for (int nj = 0; nj < 4; ++nj)
            kf[nj] = *(const bf16x8*)(Ks + (kc * 64 + nj * 16 + l15) * 32 + ((lg ^ xsw) * 8));
        #pragma unroll
        for (int mih = 0; mih < 2; ++mih) {
            f32x4 s[2][4];
            __builtin_amdgcn_s_setprio(1);
            #pragma unroll
            for (int m2 = 0; m2 < 2; ++m2) {
                int mi = mih * 2 + m2;
                #pragma unroll
                for (int nj = 0; nj < 4; ++nj) {
                    f32x4 z = {0.f, 0.f, 0.f, 0.f};
                    s[m2][nj] = __builtin_amdgcn_mfma_f32_16x16x32_bf16(kf[nj], qfrag[mi], z, 0, 0, 0);
                }
            }
            __builtin_amdgcn_s_setprio(0);
            #pragma unroll
            for (int m2 = 0; m2 < 2; ++m2) {
                int mi = mih * 2 + m2;
                #pragma unroll
                for (int nj = 0; nj < 4; ++nj) {
                    short4 bp4 = *(const short4*)(bpp + 4 * (64 * mi + 1024 * nj + 4096 * kc));
                    s[m2][nj][0] += b2f(bp4.x);
                    s[m2][nj][1] += b2f(bp4.y);
                    s[m2][nj][2] += b2f(bp4.z);
                    s[m2][nj][3] += b2f(bp4.w);
                }
            }
            #pragma unroll
            for (int m2 = 0; m2 < 2; ++m2) {
                int mi = mih * 2 + m2;
                float mx = s[m2][0][0];
                #pragma unroll
                for (int nj = 0; nj < 4; ++nj)
                    #pragma unroll
                    for (int c = 0; c < 4; ++c) mx = fmaxf(mx, s[m2][nj][c]);
                mx = fmaxf(mx, __shfl_xor(mx, 16));
                mx = fmaxf(mx, __shfl_xor(mx, 32));
                float ssum = 0.f;
                if (__all(mx - mrow[mi] <= 8.f)) {
                    float mn = mrow[mi];
                    #pragma unroll
                    for (int nj = 0; nj < 4; ++nj)
                        #pragma unroll
                        for (int c = 0; c < 4; ++c) {
                            float p = exp2f(s[m2][nj][c] - mn);
                            s[m2][nj][c] = p;
                            ssum += p;
                        }
                    ssum += __shfl_xor(ssum, 16);
                    ssum += __shfl_xor(ssum, 32);
                    lrow[mi] += ssum;
                } else {
                    float mn = fmaxf(mrow[mi], mx);
                    float scn = exp2f(mrow[mi] - mn);
                    mrow[mi] = mn;
                    #pragma unroll
                    for (int nj = 0; nj < 4; ++nj)
                        #pragma unroll
                        for (int c = 0; c < 4; ++c) {
                            float p = exp2f(s[m2][nj][c] - mn);
                            s[m2][nj][c] = p;
                            ssum += p;
                        }
                    ssum += __shfl_xor(ssum, 16);
                    ssum += __shfl_xor(ssum, 32);
                    lrow[mi] = lrow[mi] * scn + ssum;
                    f32x4 scd;
                    #pragma unroll
                    for (int r = 0; r < 4; ++r) scd[r] = __shfl(scn, 4 * lg + r);
                    O[mi][0] *= scd;
                    O[mi][1] *= scd;
                }
                #pragma unroll
                for (int nj = 0; nj < 4; ++nj)
                    *(uint2*)(Pl[w] + (m2 * 16 + l15) * PLD + nj * 16 + 4 * lg) =
                        pk4(s[m2][nj][0], s[m2][nj][1], s[m2][nj][2], s[m2][nj][3]);
            }
            // PV for this mi-pair
            #pragma unroll
            for (int kk = 0; kk < 2; ++kk) {
                bf16x8 vf[2];
                #pragma unroll
                for (int dj = 0; dj < 2; ++dj) {
                    int d = dj * 16 + l15;
                    int cb = (kc * 128 + kk * 64 + lg * 16) ^ ((l15 & 7) << 4);
                    vf[dj] = *(const bf16x8*)((const char*)Vt + d * 512 + cb);
                }
                __builtin_amdgcn_s_setprio(1);
                #pragma unroll
                for (int m2 = 0; m2 < 2; ++m2) {
                    int mi = mih * 2 + m2;
                    bf16x8 af = *(const bf16x8*)(Pl[w] + (m2 * 16 + l15) * PLD + kk * 32 + lg * 8);
                    O[mi][0] = __builtin_amdgcn_mfma_f32_16x16x32_bf16(af, vf[0], O[mi][0], 0, 0, 0);
                    O[mi][1] = __builtin_amdgcn_mfma_f32_16x16x32_bf16(af, vf[1], O[mi][1], 0, 0, 0);
                }
                __builtin_amdgcn_s_setprio(0);
            }
        }
    }

    #pragma unroll
    for (int mi = 0; mi < 4; ++mi) {
        float linv = 1.f / lrow[mi];
        f32x4 invd;
        #pragma unroll
        for (int r = 0; r < 4; ++r) invd[r] = __shfl(linv, 4 * lg + r);
        #pragma unroll
        for (int dj = 0; dj < 2; ++dj) {
            int d = dj * 16 + l15;
            if (d >= HDz) continue;
            #pragma unroll
            for (int r = 0; r < 4; ++r) {
                int q = w * 64 + mi * 16 + 4 * lg + r;
                if (q < Sz)
                    o[((size_t)b * Sp + q) * Kp + h * HDz + d] = f2b(O[mi][dj][r] * invd[r]);
            }
        }
    }
}

// ---------------- pool + fc_norm -> bf16 pooled ----------------
__global__ void pool_norm_k(const float* __restrict__ tok, const float* __restrict__ sc,
                            const float* __restrict__ bi, short* __restrict__ pooled) {
    int b = blockIdx.x;
    int t = threadIdx.x;
    float val = 0.f;
    if (t < Dz) {
        const float* base = tok + ((size_t)b * Sp + 1) * Dz + t;
        float s = 0.f;
        for (int si = 0; si < Nz; ++si) s += base[(size_t)si * Dz];
        val = s * (1.f / Nz);
    }
    __shared__ float red[8];
    float sum = val, sq = val * val;
    #pragma unroll
    for (int off = 32; off; off >>= 1) { sum += __shfl_xor(sum, off); sq += __shfl_xor(sq, off); }
    int wave = t >> 6, lane = t & 63;
    if (lane == 0) { red[wave] = sum; red[4 + wave] = sq; }
    __syncthreads();
    sum = red[0] + red[1] + red[2] + red[3];
    sq = red[4] + red[5] + red[6] + red[7];
    float mean = sum * (1.f / Dz);
    float var = sq * (1.f / Dz) - mean * mean;
    float rstd = rsqrtf(var + 1e-6f);
    if (t < Dz) pooled[(size_t)b * Kp + t] = f2b((val - mean) * rstd * sc[t] + bi[t]);
    else if (t < Kp) pooled[(size_t)b * Kp + t] = 0;
}

extern "C" void kernel_launch(void* const* d_in, const int* in_sizes, int n_in,
                              void* d_out, int out_size, void* d_ws, size_t ws_size,
                              hipStream_t stream) {
    const float* x        = (const float*)d_in[0];
    const float* conv_w   = (const float*)d_in[1];
    const float* conv_b   = (const float*)d_in[2];
    const float* cls_tok  = (const float*)d_in[3];
    const float* pos_emb  = (const float*)d_in[4];
    const float* ln1_s    = (const float*)d_in[5];
    const float* ln1_b    = (const float*)d_in[6];
    const float* qkv_w    = (const float*)d_in[7];
    const float* q_bias   = (const float*)d_in[8];
    const float* v_bias   = (const float*)d_in[9];
    const float* rpb      = (const float*)d_in[10];
    const float* proj_w   = (const float*)d_in[11];
    const float* proj_b   = (const float*)d_in[12];
    const float* ln2_s    = (const float*)d_in[13];
    const float* ln2_b    = (const float*)d_in[14];
    const float* fc1_w    = (const float*)d_in[15];
    const float* fc1_b    = (const float*)d_in[16];
    const float* fc2_w    = (const float*)d_in[17];
    const float* fc2_b    = (const float*)d_in[18];
    const float* fcn_s    = (const float*)d_in[19];
    const float* fcn_b    = (const float*)d_in[20];
    const float* head_w   = (const float*)d_in[21];
    const float* head_b   = (const float*)d_in[22];
    float* out = (float*)d_out;

    char* ws = (char*)d_ws;
    float* tok  = (float*)ws;  ws += (size_t)Mp * Dz * 4;
    short* xa   = (short*)ws;  ws += (size_t)Mp * Kp * 2;
    short* xb   = (short*)ws;  ws += (size_t)Mp * Kp * 2;
    short* xc   = (short*)ws;  ws += (size_t)Mp * Kp * 2;
    short* mid  = (short*)ws;  ws += (size_t)Mp * FFz * 2;
    short* Qb   = (short*)ws;  ws += (size_t)640 * 8192 * 2;
    short* Kb   = (short*)ws;  ws += (size_t)640 * 8192 * 2;
    short* Vtb  = (short*)ws;  ws += (size_t)640 * 8192 * 2;
    short* wq = (short*)ws;    ws += (size_t)Lz * 640 * Kp * 2;
    short* wp = (short*)ws;    ws += (size_t)Lz * 256 * Kp * 2;
    short* w1 = (short*)ws;    ws += (size_t)Lz * 896 * Kp * 2;
    short* w2 = (short*)ws;    ws += (size_t)Lz * 256 * FFz * 2;
    short* wh = (short*)ws;    ws += (size_t)1024 * Kp * 2;
    short* biasC = (short*)ws; ws += (size_t)Lz * BIASL * 2;
    short* xpb  = (short*)ws;  ws += (size_t)PEM * 64 * 2;
    short* wpe  = (short*)ws;  ws += (size_t)256 * 64 * 2;
    short* pooledb = (short*)ws; ws += (size_t)128 * Kp * 2;

    // xa pad rows feed K/V values -> must be finite (NaN there would poison softmax).
    hipMemsetAsync(xa, 0, (size_t)Mp * Kp * 2, stream);
    hipMemsetAsync(pooledb, 0, (size_t)128 * Kp * 2, stream);

    {
        int n;
        n = Lz * 640 * Kp;  cvt_pad_k<<<(n + 255) / 256, 256, 0, stream>>>(qkv_w, wq, 600, 200, 640, Kp, n);
        n = Lz * 256 * Kp;  cvt_pad_k<<<(n + 255) / 256, 256, 0, stream>>>(proj_w, wp, 200, 200, 256, Kp, n);
        n = Lz * 896 * Kp;  cvt_pad_k<<<(n + 255) / 256, 256, 0, stream>>>(fc1_w, w1, 800, 200, 896, Kp, n);
        n = Lz * 256 * FFz; cvt_pad_k<<<(n + 255) / 256, 256, 0, stream>>>(fc2_w, w2, 200, 800, 256, FFz, n);
        n = 1024 * Kp;      cvt_pad_k<<<(n + 255) / 256, 256, 0, stream>>>(head_w, wh, 1000, 200, 1024, Kp, n);
        n = 256 * 64;       cvt_pad_k<<<(n + 255) / 256, 256, 0, stream>>>(conv_w, wpe, 200, 50, 256, 64, n);
    }
    bias_pre5_k<<<dim3(640, Lz), 256, 0, stream>>>(rpb, biasC);

    xcvt_k<<<(PEM * 64) / 256, 256, 0, stream>>>(x, xpb);
    gemm8_k<4, 64, 128><<<4 * (PEM / 128), 256, 0, stream>>>(
        xpb, wpe, conv_b, nullptr, pos_emb, tok,
        nullptr, nullptr, nullptr, PEM, Dz, 64, 64, Dz, 4, PEM / 128);
    cls_k<<<Bz, 256, 0, stream>>>(cls_tok, pos_emb, tok);

    dim3 blk(256);
    ln_k<<<Mp / 4, blk, 0, stream>>>(tok, xa, ln1_s, ln1_b);
    for (int l = 0; l < Lz; ++l) {
        gemm8_k<1, 128, 64><<<5 * (Mp / 64), blk, 0, stream>>>(
            xa, wq + (size_t)l * 640 * Kp, q_bias + l * Dz, v_bias + l * Dz,
            nullptr, nullptr, Qb, Kb, Vtb,
            Mp, 600, Kp, Kp, 0, 5, Mp / 64);
        attn6_k<<<640, blk, 0, stream>>>(Qb, Kb, Vtb, biasC + (size_t)l * BIASL, xb);
        gemm8_k<2, 64, 64><<<4 * (Mp / 64), blk, 0, stream>>>(
            xb, wp + (size_t)l * 256 * Kp, proj_b + l * Dz, nullptr,
            tok, tok, nullptr, nullptr, nullptr,
            Mp, Dz, Kp, Kp, Dz, 4, Mp / 64);
        ln_k<<<Mp / 4, blk, 0, stream>>>(tok, xc, ln2_s + l * Dz, ln2_b + l * Dz);
        gemm8_k<3, 128, 64><<<7 * (Mp / 64), blk, 0, stream>>>(
            xc, w1 + (size_t)l * 896 * Kp, fc1_b + l * FFz, nullptr,
            nullptr, mid, nullptr, nullptr, nullptr,
            Mp, FFz, Kp, Kp, FFz, 7, Mp / 64);
        gemm8_k<2, 64, 64><<<4 * (Mp / 64), blk, 0, stream>>>(
            mid, w2 + (size_t)l * 256 * FFz, fc2_b + l * Dz, nullptr,
            tok, tok, nullptr, nullptr, nullptr,
            Mp, Dz, FFz, FFz, Dz, 4, Mp / 64);
        ln_k<<<Mp / 4, blk, 0, stream>>>(tok, xa, ln1_s + (size_t)((l + 1) % Lz) * Dz,
                                         ln1_b + (size_t)((l + 1) % Lz) * Dz);
    }

    pool_norm_k<<<Bz, blk, 0, stream>>>(tok, fcn_s, fcn_b, pooledb);
    gemm8_k<0, 128, 128><<<8, blk, 0, stream>>>(
        pooledb, wh, head_b, nullptr, nullptr, out,
        nullptr, nullptr, nullptr, Bz, NCz, Kp, Kp, NCz, 8, 1);
}

// Round 19
// 1351.831 us; speedup vs baseline: 1.0741x; 1.0741x over previous
//
#include <hip/hip_runtime.h>
#include <math.h>

#define Bz 64
#define Tz 12000
#define Pz 50
#define Dz 200
#define Lz 12
#define Hz 10
#define HDz 20
#define FFz 800
#define Nz 240
#define Sz 241
#define Sp 256                // padded seq stride
#define NRDz 482
#define NCz 1000
#define BS (Bz * Sz)          // 15424 valid rows
#define Mp (Bz * Sp)          // 16384 padded rows
#define Kp 224                // K=200 padded to 7*32
#define PEM (Bz * Nz)         // 15360 patch rows
#define SCALEq 0.22360679774997896f
#define LOG2E 1.4426950408889634f
#define SCALE2f (SCALEq * LOG2E)
#define BIASL 655360          // shorts per layer of bias table

typedef __attribute__((ext_vector_type(8))) short bf16x8;
typedef __attribute__((ext_vector_type(4))) float f32x4;

static __device__ __forceinline__ short f2b(float f) {
    unsigned u = __float_as_uint(f);
    unsigned r = (u + 0x7fffu + ((u >> 16) & 1u)) >> 16;
    return (short)r;
}
static __device__ __forceinline__ float b2f(short v) {
    return __uint_as_float(((unsigned)(unsigned short)v) << 16);
}
static __device__ __forceinline__ uint2 pk4(float a, float b, float c, float d) {
    uint2 r;
    asm("v_cvt_pk_bf16_f32 %0, %1, %2" : "=v"(r.x) : "v"(a), "v"(b));
    asm("v_cvt_pk_bf16_f32 %0, %1, %2" : "=v"(r.y) : "v"(c), "v"(d));
    return r;
}
static __device__ __forceinline__ float frcp(float x) {
    float r;
    asm("v_rcp_f32 %0, %1" : "=v"(r) : "v"(x));
    return r;
}
static __device__ __forceinline__ float gelu_f(float v) {
    float u = v * (0.7978845608f + 0.03567740814f * v * v);
    float e = exp2f(2.885390082f * u);
    return v * e * frcp(e + 1.f);
}
static __device__ __forceinline__ void gll16(const void* g, void* l) {
    __builtin_amdgcn_global_load_lds((const __attribute__((address_space(1))) unsigned*)g,
                                     (__attribute__((address_space(3))) unsigned*)l, 16, 0, 0);
}
template <int N> static __device__ __forceinline__ void wait_vm() {
    if constexpr (N == 0) asm volatile("s_waitcnt vmcnt(0)" ::: "memory");
    else if constexpr (N == 1) asm volatile("s_waitcnt vmcnt(1)" ::: "memory");
    else if constexpr (N == 2) asm volatile("s_waitcnt vmcnt(2)" ::: "memory");
    else if constexpr (N == 3) asm volatile("s_waitcnt vmcnt(3)" ::: "memory");
    else if constexpr (N == 4) asm volatile("s_waitcnt vmcnt(4)" ::: "memory");
    else if constexpr (N == 5) asm volatile("s_waitcnt vmcnt(5)" ::: "memory");
    else if constexpr (N == 6) asm volatile("s_waitcnt vmcnt(6)" ::: "memory");
}

// ---------------- f32 [L][N][K] -> bf16 [L][Npad][Kpad] zero-padded ----------------
__global__ void cvt_pad_k(const float* __restrict__ in, short* __restrict__ out,
                          int N, int K, int Npad, int Kpad, int total) {
    int i = blockIdx.x * 256 + threadIdx.x;
    if (i >= total) return;
    int pk = Npad * Kpad;
    int l = i / pk;
    int r = i - l * pk;
    int n = r / Kpad;
    int k = r - n * Kpad;
    float v = (n < N && k < K) ? in[((size_t)l * N + n) * K + k] : 0.f;
    out[i] = f2b(v);
}

// ---------------- x -> bf16 patches [15360][64] ----------------
__global__ void xcvt_k(const float* __restrict__ x, short* __restrict__ xb) {
    int i = blockIdx.x * 256 + threadIdx.x;
    int m = i >> 6, k = i & 63;
    int b = m / Nz, j = m - b * Nz;
    xb[i] = (k < Pz) ? f2b(x[(size_t)b * Tz + j * Pz + k]) : 0;
}

// ---------------- cls rows ----------------
__global__ void cls_k(const float* __restrict__ cls, const float* __restrict__ pos,
                      float* __restrict__ tok) {
    int b = blockIdx.x, d = threadIdx.x;
    if (d < Dz) tok[(size_t)b * Sp * Dz + d] = cls[d] + pos[d];
}

// ---------------- layernorm v2 (vectorized): f32 (ld 200) -> bf16 (ld 224) ----------
__global__ void ln_k(const float* __restrict__ in, short* __restrict__ out,
                     const float* __restrict__ sc, const float* __restrict__ bi) {
    int wave = threadIdx.x >> 6, lane = threadIdx.x & 63;
    int row = blockIdx.x * 4 + wave;
    if ((row & 255) >= Sz) return;
    const float* x = in + (size_t)row * Dz;
    f32x4 v = {0.f, 0.f, 0.f, 0.f};
    if (lane < 50) v = *(const f32x4*)(x + lane * 4);
    float sum = v[0] + v[1] + v[2] + v[3];
    #pragma unroll
    for (int off = 32; off; off >>= 1) sum += __shfl_xor(sum, off);
    float mean = sum * (1.f / Dz);
    float var = 0.f;
    if (lane < 50) {
        #pragma unroll
        for (int i = 0; i < 4; ++i) { float d = v[i] - mean; var += d * d; }
    }
    #pragma unroll
    for (int off = 32; off; off >>= 1) var += __shfl_xor(var, off);
    float rstd = rsqrtf(var * (1.f / Dz) + 1e-6f);
    short* o = out + (size_t)row * Kp;
    if (lane < 50) {
        f32x4 s4 = *(const f32x4*)(sc + lane * 4);
        f32x4 b4 = *(const f32x4*)(bi + lane * 4);
        short4 o4;
        #pragma unroll
        for (int r = 0; r < 4; ++r)
            ((short*)&o4)[r] = f2b((v[r] - mean) * rstd * s4[r] + b4[r]);
        *(short4*)(o + lane * 4) = o4;
    } else if (lane < 56) {
        short4 z = {0, 0, 0, 0};
        *(short4*)(o + lane * 4) = z;
    }
}

// ---------------- bias precompute (ALL layers), split q-halves fragment order --------
// short4 idx = lane + 64*mi + 128*w + 512*qb + 1024*nj + 4096*kc + 16384*h (+ l*163840)
// q = qb*128 + w*32 + mi*16 + (lane&15);  k = kc*64 + nj*16 + 4*(lane>>4) + r
__global__ void bias_pre4_k(const float* __restrict__ tabs, short* __restrict__ bp) {
    int l = blockIdx.y;
    int tid = blockIdx.x * 256 + threadIdx.x;
    const float* tab = tabs + (size_t)l * NRDz * Hz;
    int lane = tid & 63;
    int mi = (tid >> 6) & 1;
    int w  = (tid >> 7) & 3;
    int qb = (tid >> 9) & 1;
    int nj = (tid >> 10) & 3;
    int kc = (tid >> 12) & 3;
    int h  = tid >> 14;
    int q  = qb * 128 + w * 32 + mi * 16 + (lane & 15);
    int k0 = kc * 64 + nj * 16 + 4 * (lane >> 4);
    short4 o;
    #pragma unroll
    for (int r = 0; r < 4; ++r) {
        int k = k0 + r;
        float v;
        if (q > Nz || k > Nz) v = -1e30f;
        else if (k == 0)      v = (q == 0) ? tab[481 * Hz + h] : tab[480 * Hz + h];
        else if (q == 0)      v = tab[479 * Hz + h];
        else                  v = tab[(q - k + 239) * Hz + h];
        ((short*)&o)[r] = f2b(v * LOG2E);
    }
    *(short4*)(bp + (size_t)l * BIASL + (size_t)tid * 4) = o;
}

// ---------------- MFMA GEMM v8 (unchanged from r17) ----------
template <int MODE, int BN2, int BM2>
__global__ __launch_bounds__(256) void gemm8_k(
        const short* __restrict__ A, const short* __restrict__ W,
        const float* __restrict__ bias, const float* __restrict__ bias2,
        const float* __restrict__ res, void* __restrict__ outv,
        short* __restrict__ qo, short* __restrict__ ko, short* __restrict__ vo,
        int M, int Nreal, int K, int strideA, int ldo, int gridx, int gridy) {
    constexpr int NJ = BN2 / 32;
    constexpr int MI = BM2 / 32;
    constexpr int AISS = BM2 / 64;
    constexpr int BISS = BN2 / 64;
    constexpr int LPS = AISS + BISS;
    __shared__ short smem[3 * (BM2 + BN2) * 32];
    short* Asb = smem;
    short* Bsb = smem + 3 * BM2 * 32;
    const int t = threadIdx.x;
    const int lane = t & 63, w = t >> 6;
    const int l15 = lane & 15, lg = lane >> 4;
    const int wm = w & 1, wn = w >> 1;

    int bx, by;
    {
        int wg = blockIdx.x;
        if ((gridy & 7) == 0) {
            int xcd = wg & 7, j = wg >> 3;
            bx = j % gridx;
            by = (j / gridx) * 8 + xcd;
        } else {
            bx = wg % gridx;
            by = wg / gridx;
        }
    }
    const int row0 = by * BM2, col0 = bx * BN2;
    const int xsw = (l15 >> 1) & 3;

    f32x4 acc[MI][NJ];
    #pragma unroll
    for (int mi = 0; mi < MI; ++mi)
        #pragma unroll
        for (int nj = 0; nj < NJ; ++nj) {
            f32x4 z = {0.f, 0.f, 0.f, 0.f};
            acc[mi][nj] = z;
        }

    const int nk = K >> 5;

    auto stage = [&](int buf, int kt) {
        const int k0 = kt * 32;
        #pragma unroll
        for (int i = 0; i < AISS; ++i) {
            int c = (w * AISS + i) * 64 + lane;
            int r = c >> 2, q = c & 3;
            const short* gp = A + (size_t)(row0 + r) * strideA + k0 + ((q ^ ((r >> 1) & 3)) * 8);
            gll16(gp, Asb + buf * BM2 * 32 + (w * AISS + i) * 512);
        }
        #pragma unroll
        for (int i = 0; i < BISS; ++i) {
            int c = (w * BISS + i) * 64 + lane;
            int r = c >> 2, q = c & 3;
            const short* gp = W + (size_t)(col0 + r) * K + k0 + ((q ^ ((r >> 1) & 3)) * 8);
            gll16(gp, Bsb + buf * BN2 * 32 + (w * BISS + i) * 512);
        }
    };

    stage(0, 0);
    if (nk > 1) stage(1, 1);
    for (int kt = 0; kt < nk; ++kt) {
        const int cur = kt % 3;
        if (kt + 1 < nk) wait_vm<LPS>();
        else             wait_vm<0>();
        __builtin_amdgcn_s_barrier();
        if (kt + 2 < nk) stage((kt + 2) % 3, kt + 2);
        bf16x8 bfr[NJ], afr[MI];
        #pragma unroll
        for (int nj = 0; nj < NJ; ++nj)
            bfr[nj] = *(const bf16x8*)(Bsb + cur * BN2 * 32 + (wn * (BN2 / 2) + nj * 16 + l15) * 32 + ((lg ^ xsw) * 8));
        #pragma unroll
        for (int mi = 0; mi < MI; ++mi)
            afr[mi] = *(const bf16x8*)(Asb + cur * BM2 * 32 + (wm * (BM2 / 2) + mi * 16 + l15) * 32 + ((lg ^ xsw) * 8));
        #pragma unroll
        for (int mi = 0; mi < MI; ++mi)
            #pragma unroll
            for (int nj = 0; nj < NJ; ++nj) {
                if (MODE == 1)
                    acc[mi][nj] = __builtin_amdgcn_mfma_f32_16x16x32_bf16(bfr[nj], afr[mi], acc[mi][nj], 0, 0, 0);
                else
                    acc[mi][nj] = __builtin_amdgcn_mfma_f32_16x16x32_bf16(afr[mi], bfr[nj], acc[mi][nj], 0, 0, 0);
            }
    }

    if (MODE == 1) {
        #pragma unroll
        for (int mi = 0; mi < MI; ++mi) {
            int m = row0 + wm * (BM2 / 2) + mi * 16 + l15;
            int b = m >> 8, s = m & 255;
            #pragma unroll
            for (int nj = 0; nj < NJ; ++nj) {
                int n0 = col0 + wn * (BN2 / 2) + nj * 16 + 4 * lg;
                if (n0 >= 600) continue;
                int which = n0 >= 400 ? 2 : (n0 >= 200 ? 1 : 0);
                int hd = n0 - which * 200;
                int h = hd / 20, d0 = hd - h * 20;
                size_t base = (size_t)(b * Hz + h) * 8192;
                if (which == 0) {
                    f32x4 qb4 = *(const f32x4*)(bias + hd);
                    short4 o4;
                    #pragma unroll
                    for (int r = 0; r < 4; ++r)
                        ((short*)&o4)[r] = f2b((acc[mi][nj][r] + qb4[r]) * SCALE2f);
                    *(short4*)(qo + base + s * 32 + d0) = o4;
                } else if (which == 1) {
                    int oct = (d0 >> 3) ^ ((s >> 1) & 3);
                    short4 o4;
                    #pragma unroll
                    for (int r = 0; r < 4; ++r)
                        ((short*)&o4)[r] = f2b(acc[mi][nj][r]);
                    *(short4*)(ko + base + s * 32 + oct * 8 + (d0 & 7)) = o4;
                } else {
                    f32x4 vb4 = *(const f32x4*)(bias2 + hd);
                    #pragma unroll
                    for (int r = 0; r < 4; ++r) {
                        int d = d0 + r;
                        vo[base + d * 256 + (s ^ ((d & 7) << 3))] = f2b(acc[mi][nj][r] + vb4[r]);
                    }
                }
            }
        }
        return;
    }

    if (MODE == 2 || MODE == 3) {
        __syncthreads();
        if (MODE == 3) {
            constexpr int EW = BN2 + 8;
            short* ep = smem;
            #pragma unroll
            for (int mi = 0; mi < MI; ++mi)
                #pragma unroll
                for (int nj = 0; nj < NJ; ++nj) {
                    int nl = wn * (BN2 / 2) + nj * 16 + l15;
                    int n = col0 + nl;
                    float bv = (n < Nreal) ? bias[n] : 0.f;
                    #pragma unroll
                    for (int r = 0; r < 4; ++r)
                        ep[(wm * (BM2 / 2) + mi * 16 + 4 * lg + r) * EW + nl] =
                            f2b(gelu_f(acc[mi][nj][r] + bv));
                }
            __syncthreads();
            constexpr int TPR = BN2 / 8;
            constexpr int RPP = 256 / TPR;
            int rowp = t / TPR, cch = t % TPR;
            #pragma unroll
            for (int p = 0; p < BM2 / RPP; ++p) {
                int row = p * RPP + rowp;
                int n = col0 + cch * 8;
                if (n + 8 <= Nreal)
                    *(bf16x8*)((short*)outv + (size_t)(row0 + row) * ldo + n) =
                        *(const bf16x8*)(ep + row * EW + cch * 8);
            }
        } else {
            constexpr int EWF = BN2 + 4;
            float* epf = (float*)smem;
            #pragma unroll
            for (int mi = 0; mi < MI; ++mi)
                #pragma unroll
                for (int nj = 0; nj < NJ; ++nj) {
                    int nl = wn * (BN2 / 2) + nj * 16 + l15;
                    int n = col0 + nl;
                    float bv = (n < Nreal) ? bias[n] : 0.f;
                    #pragma unroll
                    for (int r = 0; r < 4; ++r)
                        epf[(wm * (BM2 / 2) + mi * 16 + 4 * lg + r) * EWF + nl] =
                            acc[mi][nj][r] + bv;
                }
            __syncthreads();
            constexpr int TPR = BN2 / 4;
            constexpr int RPP = 256 / TPR;
            int rowp = t / TPR, cch = t % TPR;
            #pragma unroll
            for (int p = 0; p < BM2 / RPP; ++p) {
                int row = p * RPP + rowp;
                int n = col0 + cch * 4;
                if (n + 4 <= Nreal) {
                    size_t off = (size_t)(row0 + row) * ldo + n;
                    f32x4 v = *(const f32x4*)(epf + row * EWF + cch * 4);
                    f32x4 rr = *(const f32x4*)(res + off);
                    *(f32x4*)((float*)outv + off) = v + rr;
                }
            }
        }
        return;
    }

    #pragma unroll
    for (int mi = 0; mi < MI; ++mi) {
        #pragma unroll
        for (int nj = 0; nj < NJ; ++nj) {
            int n = col0 + wn * (BN2 / 2) + nj * 16 + l15;
            if (n >= Nreal) continue;
            if (MODE == 4) {
                #pragma unroll
                for (int r = 0; r < 4; ++r) {
                    int m = row0 + wm * (BM2 / 2) + mi * 16 + 4 * lg + r;
                    int bb = m / Nz, j = m - bb * Nz;
                    size_t trow = (size_t)bb * Sp + j + 1;
                    ((float*)outv)[trow * ldo + n] =
                        acc[mi][nj][r] + bias[n] + res[(size_t)(j + 1) * Dz + n];
                }
            } else {
                #pragma unroll
                for (int r = 0; r < 4; ++r) {
                    int m = row0 + wm * (BM2 / 2) + mi * 16 + 4 * lg + r;
                    if (m >= M) continue;
                    size_t off = (size_t)m * ldo + n;
                    ((float*)outv)[off] = acc[mi][nj][r] + bias[n];
                }
            }
        }
    }
}

// ---------------- MFMA attention v5 (r17 version: 1280 blocks, 2 q-halves) ----------
#define PLD 72
__global__ __launch_bounds__(256) void attn5_k(const short* __restrict__ Qb,
                                               const short* __restrict__ Kb,
                                               const short* __restrict__ Vtb,
                                               const short* __restrict__ biasC,
                                               short* __restrict__ o) {
    const int blk = blockIdx.x;
    const int qb = blk & 1;
    const int bh = blk >> 1;
    const int b = bh / Hz, h = bh - b * Hz;
    __shared__ short Ks[8192];
    __shared__ short Vt[8192];
    __shared__ short Pl[4][32 * PLD];
    const int t = threadIdx.x;
    const int lane = t & 63, w = t >> 6;
    const int l15 = lane & 15, lg = lane >> 4;

    const short* kbh = Kb + (size_t)bh * 8192;
    const short* vbh = Vtb + (size_t)bh * 8192;
    #pragma unroll
    for (int i = 0; i < 4; ++i) {
        int j = w * 4 + i;
        gll16(kbh + (size_t)(j * 64 + lane) * 8, Ks + j * 512);
        gll16(vbh + (size_t)(j * 64 + lane) * 8, Vt + j * 512);
    }
    bf16x8 qfrag[2];
    const short* qbh = Qb + (size_t)bh * 8192;
    #pragma unroll
    for (int mi = 0; mi < 2; ++mi) {
        int qrow = qb * 128 + w * 32 + mi * 16 + l15;
        qfrag[mi] = *(const bf16x8*)(qbh + qrow * 32 + lg * 8);
    }
    const short* bpp = biasC + 4 * (size_t)(lane + 128 * w + 512 * qb + 16384 * h);
    __syncthreads();

    f32x4 O[2][2];
    float mrow[2] = {-1e30f, -1e30f};
    float lrow[2] = {0.f, 0.f};
    {
        f32x4 z = {0.f, 0.f, 0.f, 0.f};
        O[0][0] = z; O[0][1] = z; O[1][0] = z; O[1][1] = z;
    }
    const int xsw = (l15 >> 1) & 3;

    #pragma unroll 1
    for (int kc = 0; kc < 4; ++kc) {
        bf16x8 kf[4];
        #pragma unroll
        for (int nj = 0; nj < 4; ++nj)
            kf[nj] = *(const bf16x8*)(Ks + (kc * 64 + nj * 16 + l15) * 32 + ((lg ^ xsw) * 8));
        f32x4 s[2][4];
        __builtin_amdgcn_s_setprio(1);
        #pragma unroll
        for (int mi = 0; mi < 2; ++mi)
            #pragma unroll
            for (int nj = 0; nj < 4; ++nj) {
                f32x4 z = {0.f, 0.f, 0.f, 0.f};
                s[mi][nj] = __builtin_amdgcn_mfma_f32_16x16x32_bf16(kf[nj], qfrag[mi], z, 0, 0, 0);
            }
        __builtin_amdgcn_s_setprio(0);
        const short* bkc = bpp + kc * 16384;
        #pragma unroll
        for (int mi = 0; mi < 2; ++mi)
            #pragma unroll
            for (int nj = 0; nj < 4; ++nj) {
                short4 bp4 = *(const short4*)(bkc + nj * 4096 + mi * 256);
                s[mi][nj][0] += b2f(bp4.x);
                s[mi][nj][1] += b2f(bp4.y);
                s[mi][nj][2] += b2f(bp4.z);
                s[mi][nj][3] += b2f(bp4.w);
            }
        #pragma unroll
        for (int mi = 0; mi < 2; ++mi) {
            float mx = s[mi][0][0];
            #pragma unroll
            for (int nj = 0; nj < 4; ++nj)
                #pragma unroll
                for (int c = 0; c < 4; ++c) mx = fmaxf(mx, s[mi][nj][c]);
            mx = fmaxf(mx, __shfl_xor(mx, 16));
            mx = fmaxf(mx, __shfl_xor(mx, 32));
            float ssum = 0.f;
            if (__all(mx - mrow[mi] <= 8.f)) {
                float mn = mrow[mi];
                #pragma unroll
                for (int nj = 0; nj < 4; ++nj)
                    #pragma unroll
                    for (int c = 0; c < 4; ++c) {
                        float p = exp2f(s[mi][nj][c] - mn);
                        s[mi][nj][c] = p;
                        ssum += p;
                    }
                ssum += __shfl_xor(ssum, 16);
                ssum += __shfl_xor(ssum, 32);
                lrow[mi] += ssum;
            } else {
                float mn = fmaxf(mrow[mi], mx);
                float scn = exp2f(mrow[mi] - mn);
                mrow[mi] = mn;
                #pragma unroll
                for (int nj = 0; nj < 4; ++nj)
                    #pragma unroll
                    for (int c = 0; c < 4; ++c) {
                        float p = exp2f(s[mi][nj][c] - mn);
                        s[mi][nj][c] = p;
                        ssum += p;
                    }
                ssum += __shfl_xor(ssum, 16);
                ssum += __shfl_xor(ssum, 32);
                lrow[mi] = lrow[mi] * scn + ssum;
                f32x4 scd;
                #pragma unroll
                for (int r = 0; r < 4; ++r) scd[r] = __shfl(scn, 4 * lg + r);
                O[mi][0] *= scd;
                O[mi][1] *= scd;
            }
            #pragma unroll
            for (int nj = 0; nj < 4; ++nj)
                *(uint2*)(Pl[w] + (mi * 16 + l15) * PLD + nj * 16 + 4 * lg) =
                    pk4(s[mi][nj][0], s[mi][nj][1], s[mi][nj][2], s[mi][nj][3]);
        }
        #pragma unroll
        for (int kk = 0; kk < 2; ++kk) {
            bf16x8 vf[2];
            #pragma unroll
            for (int dj = 0; dj < 2; ++dj) {
                int d = dj * 16 + l15;
                int cb = (kc * 128 + kk * 64 + lg * 16) ^ ((l15 & 7) << 4);
                vf[dj] = *(const bf16x8*)((const char*)Vt + d * 512 + cb);
            }
            __builtin_amdgcn_s_setprio(1);
            #pragma unroll
            for (int mi = 0; mi < 2; ++mi) {
                bf16x8 af = *(const bf16x8*)(Pl[w] + (mi * 16 + l15) * PLD + kk * 32 + lg * 8);
                O[mi][0] = __builtin_amdgcn_mfma_f32_16x16x32_bf16(af, vf[0], O[mi][0], 0, 0, 0);
                O[mi][1] = __builtin_amdgcn_mfma_f32_16x16x32_bf16(af, vf[1], O[mi][1], 0, 0, 0);
            }
            __builtin_amdgcn_s_setprio(0);
        }
    }

    #pragma unroll
    for (int mi = 0; mi < 2; ++mi) {
        float linv = 1.f / lrow[mi];
        f32x4 invd;
        #pragma unroll
        for (int r = 0; r < 4; ++r) invd[r] = __shfl(linv, 4 * lg + r);
        #pragma unroll
        for (int dj = 0; dj < 2; ++dj) {
            int d = dj * 16 + l15;
            if (d >= HDz) continue;
            #pragma unroll
            for (int r = 0; r < 4; ++r) {
                int q = qb * 128 + w * 32 + mi * 16 + 4 * lg + r;
                if (q < Sz)
                    o[((size_t)b * Sp + q) * Kp + h * HDz + d] = f2b(O[mi][dj][r] * invd[r]);
            }
        }
    }
}

// ---------------- pool + fc_norm -> bf16 pooled ----------------
__global__ void pool_norm_k(const float* __restrict__ tok, const float* __restrict__ sc,
                            const float* __restrict__ bi, short* __restrict__ pooled) {
    int b = blockIdx.x;
    int t = threadIdx.x;
    float val = 0.f;
    if (t < Dz) {
        const float* base = tok + ((size_t)b * Sp + 1) * Dz + t;
        float s = 0.f;
        for (int si = 0; si < Nz; ++si) s += base[(size_t)si * Dz];
        val = s * (1.f / Nz);
    }
    __shared__ float red[8];
    float sum = val, sq = val * val;
    #pragma unroll
    for (int off = 32; off; off >>= 1) { sum += __shfl_xor(sum, off); sq += __shfl_xor(sq, off); }
    int wave = t >> 6, lane = t & 63;
    if (lane == 0) { red[wave] = sum; red[4 + wave] = sq; }
    __syncthreads();
    sum = red[0] + red[1] + red[2] + red[3];
    sq = red[4] + red[5] + red[6] + red[7];
    float mean = sum * (1.f / Dz);
    float var = sq * (1.f / Dz) - mean * mean;
    float rstd = rsqrtf(var + 1e-6f);
    if (t < Dz) pooled[(size_t)b * Kp + t] = f2b((val - mean) * rstd * sc[t] + bi[t]);
    else if (t < Kp) pooled[(size_t)b * Kp + t] = 0;
}

extern "C" void kernel_launch(void* const* d_in, const int* in_sizes, int n_in,
                              void* d_out, int out_size, void* d_ws, size_t ws_size,
                              hipStream_t stream) {
    const float* x        = (const float*)d_in[0];
    const float* conv_w   = (const float*)d_in[1];
    const float* conv_b   = (const float*)d_in[2];
    const float* cls_tok  = (const float*)d_in[3];
    const float* pos_emb  = (const float*)d_in[4];
    const float* ln1_s    = (const float*)d_in[5];
    const float* ln1_b    = (const float*)d_in[6];
    const float* qkv_w    = (const float*)d_in[7];
    const float* q_bias   = (const float*)d_in[8];
    const float* v_bias   = (const float*)d_in[9];
    const float* rpb      = (const float*)d_in[10];
    const float* proj_w   = (const float*)d_in[11];
    const float* proj_b   = (const float*)d_in[12];
    const float* ln2_s    = (const float*)d_in[13];
    const float* ln2_b    = (const float*)d_in[14];
    const float* fc1_w    = (const float*)d_in[15];
    const float* fc1_b    = (const float*)d_in[16];
    const float* fc2_w    = (const float*)d_in[17];
    const float* fc2_b    = (const float*)d_in[18];
    const float* fcn_s    = (const float*)d_in[19];
    const float* fcn_b    = (const float*)d_in[20];
    const float* head_w   = (const float*)d_in[21];
    const float* head_b   = (const float*)d_in[22];
    float* out = (float*)d_out;

    char* ws = (char*)d_ws;
    float* tok  = (float*)ws;  ws += (size_t)Mp * Dz * 4;
    short* xa   = (short*)ws;  ws += (size_t)Mp * Kp * 2;
    short* xb   = (short*)ws;  ws += (size_t)Mp * Kp * 2;
    short* xc   = (short*)ws;  ws += (size_t)Mp * Kp * 2;
    short* mid  = (short*)ws;  ws += (size_t)Mp * FFz * 2;
    short* Qb   = (short*)ws;  ws += (size_t)640 * 8192 * 2;
    short* Kb   = (short*)ws;  ws += (size_t)640 * 8192 * 2;
    short* Vtb  = (short*)ws;  ws += (size_t)640 * 8192 * 2;
    short* wq = (short*)ws;    ws += (size_t)Lz * 640 * Kp * 2;
    short* wp = (short*)ws;    ws += (size_t)Lz * 256 * Kp * 2;
    short* w1 = (short*)ws;    ws += (size_t)Lz * 896 * Kp * 2;
    short* w2 = (short*)ws;    ws += (size_t)Lz * 256 * FFz * 2;
    short* wh = (short*)ws;    ws += (size_t)1024 * Kp * 2;
    short* biasC = (short*)ws; ws += (size_t)Lz * BIASL * 2;
    short* xpb  = (short*)ws;  ws += (size_t)PEM * 64 * 2;
    short* wpe  = (short*)ws;  ws += (size_t)256 * 64 * 2;
    short* pooledb = (short*)ws; ws += (size_t)128 * Kp * 2;

    // xa pad rows feed K/V values -> must be finite (NaN there would poison softmax).
    hipMemsetAsync(xa, 0, (size_t)Mp * Kp * 2, stream);
    hipMemsetAsync(pooledb, 0, (size_t)128 * Kp * 2, stream);

    {
        int n;
        n = Lz * 640 * Kp;  cvt_pad_k<<<(n + 255) / 256, 256, 0, stream>>>(qkv_w, wq, 600, 200, 640, Kp, n);
        n = Lz * 256 * Kp;  cvt_pad_k<<<(n + 255) / 256, 256, 0, stream>>>(proj_w, wp, 200, 200, 256, Kp, n);
        n = Lz * 896 * Kp;  cvt_pad_k<<<(n + 255) / 256, 256, 0, stream>>>(fc1_w, w1, 800, 200, 896, Kp, n);
        n = Lz * 256 * FFz; cvt_pad_k<<<(n + 255) / 256, 256, 0, stream>>>(fc2_w, w2, 200, 800, 256, FFz, n);
        n = 1024 * Kp;      cvt_pad_k<<<(n + 255) / 256, 256, 0, stream>>>(head_w, wh, 1000, 200, 1024, Kp, n);
        n = 256 * 64;       cvt_pad_k<<<(n + 255) / 256, 256, 0, stream>>>(conv_w, wpe, 200, 50, 256, 64, n);
    }
    bias_pre4_k<<<dim3(640, Lz), 256, 0, stream>>>(rpb, biasC);

    xcvt_k<<<(PEM * 64) / 256, 256, 0, stream>>>(x, xpb);
    gemm8_k<4, 64, 128><<<4 * (PEM / 128), 256, 0, stream>>>(
        xpb, wpe, conv_b, nullptr, pos_emb, tok,
        nullptr, nullptr, nullptr, PEM, Dz, 64, 64, Dz, 4, PEM / 128);
    cls_k<<<Bz, 256, 0, stream>>>(cls_tok, pos_emb, tok);

    dim3 blk(256);
    ln_k<<<Mp / 4, blk, 0, stream>>>(tok, xa, ln1_s, ln1_b);
    for (int l = 0; l < Lz; ++l) {
        gemm8_k<1, 128, 64><<<5 * (Mp / 64), blk, 0, stream>>>(
            xa, wq + (size_t)l * 640 * Kp, q_bias + l * Dz, v_bias + l * Dz,
            nullptr, nullptr, Qb, Kb, Vtb,
            Mp, 600, Kp, Kp, 0, 5, Mp / 64);
        attn5_k<<<1280, blk, 0, stream>>>(Qb, Kb, Vtb, biasC + (size_t)l * BIASL, xb);
        gemm8_k<2, 64, 64><<<4 * (Mp / 64), blk, 0, stream>>>(
            xb, wp + (size_t)l * 256 * Kp, proj_b + l * Dz, nullptr,
            tok, tok, nullptr, nullptr, nullptr,
            Mp, Dz, Kp, Kp, Dz, 4, Mp / 64);
        ln_k<<<Mp / 4, blk, 0, stream>>>(tok, xc, ln2_s + l * Dz, ln2_b + l * Dz);
        gemm8_k<3, 128, 64><<<7 * (Mp / 64), blk, 0, stream>>>(
            xc, w1 + (size_t)l * 896 * Kp, fc1_b + l * FFz, nullptr,
            nullptr, mid, nullptr, nullptr, nullptr,
            Mp, FFz, Kp, Kp, FFz, 7, Mp / 64);
        gemm8_k<2, 64, 64><<<4 * (Mp / 64), blk, 0, stream>>>(
            mid, w2 + (size_t)l * 256 * FFz, fc2_b + l * Dz, nullptr,
            tok, tok, nullptr, nullptr, nullptr,
            Mp, Dz, FFz, FFz, Dz, 4, Mp / 64);
        ln_k<<<Mp / 4, blk, 0, stream>>>(tok, xa, ln1_s + (size_t)((l + 1) % Lz) * Dz,
                                         ln1_b + (size_t)((l + 1) % Lz) * Dz);
    }

    pool_norm_k<<<Bz, blk, 0, stream>>>(tok, fcn_s, fcn_b, pooledb);
    gemm8_k<0, 128, 128><<<8, blk, 0, stream>>>(
        pooledb, wh, head_b, nullptr, nullptr, out,
        nullptr, nullptr, nullptr, Bz, NCz, Kp, Kp, NCz, 8, 1);
}

// Round 20
// 1334.311 us; speedup vs baseline: 1.0883x; 1.0131x over previous
//
#include <hip/hip_runtime.h>
#include <math.h>

#define Bz 64
#define Tz 12000
#define Pz 50
#define Dz 200
#define Lz 12
#define Hz 10
#define HDz 20
#define FFz 800
#define Nz 240
#define Sz 241
#define Sp 256                // padded seq stride
#define NRDz 482
#define NCz 1000
#define BS (Bz * Sz)          // 15424 valid rows
#define Mp (Bz * Sp)          // 16384 padded rows
#define Kp 224                // K=200 padded to 7*32
#define PEM (Bz * Nz)         // 15360 patch rows
#define SCALEq 0.22360679774997896f
#define LOG2E 1.4426950408889634f
#define SCALE2f (SCALEq * LOG2E)
#define BIASL 655360          // shorts per layer of bias table

typedef __attribute__((ext_vector_type(8))) short bf16x8;
typedef __attribute__((ext_vector_type(4))) float f32x4;

static __device__ __forceinline__ short f2b(float f) {
    unsigned u = __float_as_uint(f);
    unsigned r = (u + 0x7fffu + ((u >> 16) & 1u)) >> 16;
    return (short)r;
}
static __device__ __forceinline__ float b2f(short v) {
    return __uint_as_float(((unsigned)(unsigned short)v) << 16);
}
static __device__ __forceinline__ uint2 pk4(float a, float b, float c, float d) {
    uint2 r;
    asm("v_cvt_pk_bf16_f32 %0, %1, %2" : "=v"(r.x) : "v"(a), "v"(b));
    asm("v_cvt_pk_bf16_f32 %0, %1, %2" : "=v"(r.y) : "v"(c), "v"(d));
    return r;
}
static __device__ __forceinline__ float frcp(float x) {
    float r;
    asm("v_rcp_f32 %0, %1" : "=v"(r) : "v"(x));
    return r;
}
static __device__ __forceinline__ float gelu_f(float v) {
    float u = v * (0.7978845608f + 0.03567740814f * v * v);
    float e = exp2f(2.885390082f * u);
    return v * e * frcp(e + 1.f);
}
static __device__ __forceinline__ void gll16(const void* g, void* l) {
    __builtin_amdgcn_global_load_lds((const __attribute__((address_space(1))) unsigned*)g,
                                     (__attribute__((address_space(3))) unsigned*)l, 16, 0, 0);
}
template <int N> static __device__ __forceinline__ void wait_vm() {
    if constexpr (N == 0) asm volatile("s_waitcnt vmcnt(0)" ::: "memory");
    else if constexpr (N == 1) asm volatile("s_waitcnt vmcnt(1)" ::: "memory");
    else if constexpr (N == 2) asm volatile("s_waitcnt vmcnt(2)" ::: "memory");
    else if constexpr (N == 3) asm volatile("s_waitcnt vmcnt(3)" ::: "memory");
    else if constexpr (N == 4) asm volatile("s_waitcnt vmcnt(4)" ::: "memory");
    else if constexpr (N == 5) asm volatile("s_waitcnt vmcnt(5)" ::: "memory");
    else if constexpr (N == 6) asm volatile("s_waitcnt vmcnt(6)" ::: "memory");
}

// ---------------- fused weight conversion: all 6 tensors in one launch ----------------
// wbase = wq|wp|w1|w2|wh contiguous; wpe separate.
#define SEG0 1720320   // wq  : 12*640*224
#define SEG1 2408448   // +wp : 12*256*224
#define SEG2 4816896   // +w1 : 12*896*224
#define SEG3 7274496   // +w2 : 12*256*800
#define SEG4 7503872   // +wh : 1024*224
#define SEG5 7520256   // +wpe: 256*64
__global__ void cvt_all_k(const float* __restrict__ qkv_w, const float* __restrict__ proj_w,
                          const float* __restrict__ fc1_w, const float* __restrict__ fc2_w,
                          const float* __restrict__ head_w, const float* __restrict__ conv_w,
                          short* __restrict__ wbase, short* __restrict__ wpe) {
    int i = blockIdx.x * 256 + threadIdx.x;
    if (i >= SEG5) return;
    if (i < SEG4) {
        const float* src;
        int N, K, Npad, Kpad, j = i;
        if (j < SEG0)      { src = qkv_w;  N = 600;  K = 200; Npad = 640;  Kpad = 224; }
        else if (j < SEG1) { j -= SEG0; src = proj_w; N = 200; K = 200; Npad = 256; Kpad = 224; }
        else if (j < SEG2) { j -= SEG1; src = fc1_w;  N = 800; K = 200; Npad = 896; Kpad = 224; }
        else if (j < SEG3) { j -= SEG2; src = fc2_w;  N = 200; K = 800; Npad = 256; Kpad = 800; }
        else               { j -= SEG3; src = head_w; N = 1000; K = 200; Npad = 1024; Kpad = 224; }
        int pk = Npad * Kpad;
        int l = j / pk;
        int r = j - l * pk;
        int n = r / Kpad;
        int k = r - n * Kpad;
        float v = (n < N && k < K) ? src[((size_t)l * N + n) * K + k] : 0.f;
        wbase[i] = f2b(v);
    } else {
        int j = i - SEG4;
        int n = j >> 6, k = j & 63;
        wpe[j] = (n < Dz && k < Pz) ? f2b(conv_w[n * Pz + k]) : 0;
    }
}

// ---------------- x -> bf16 patches [15360][64] ----------------
__global__ void xcvt_k(const float* __restrict__ x, short* __restrict__ xb) {
    int i = blockIdx.x * 256 + threadIdx.x;
    int m = i >> 6, k = i & 63;
    int b = m / Nz, j = m - b * Nz;
    xb[i] = (k < Pz) ? f2b(x[(size_t)b * Tz + j * Pz + k]) : 0;
}

// ---------------- cls rows ----------------
__global__ void cls_k(const float* __restrict__ cls, const float* __restrict__ pos,
                      float* __restrict__ tok) {
    int b = blockIdx.x, d = threadIdx.x;
    if (d < Dz) tok[(size_t)b * Sp * Dz + d] = cls[d] + pos[d];
}

// ---------------- layernorm (vectorized): f32 (ld 200) -> bf16 (ld 224) ----------
__global__ void ln_k(const float* __restrict__ in, short* __restrict__ out,
                     const float* __restrict__ sc, const float* __restrict__ bi) {
    int wave = threadIdx.x >> 6, lane = threadIdx.x & 63;
    int row = blockIdx.x * 4 + wave;
    if ((row & 255) >= Sz) return;
    const float* x = in + (size_t)row * Dz;
    f32x4 v = {0.f, 0.f, 0.f, 0.f};
    if (lane < 50) v = *(const f32x4*)(x + lane * 4);
    float sum = v[0] + v[1] + v[2] + v[3];
    #pragma unroll
    for (int off = 32; off; off >>= 1) sum += __shfl_xor(sum, off);
    float mean = sum * (1.f / Dz);
    float var = 0.f;
    if (lane < 50) {
        #pragma unroll
        for (int i = 0; i < 4; ++i) { float d = v[i] - mean; var += d * d; }
    }
    #pragma unroll
    for (int off = 32; off; off >>= 1) var += __shfl_xor(var, off);
    float rstd = rsqrtf(var * (1.f / Dz) + 1e-6f);
    short* o = out + (size_t)row * Kp;
    if (lane < 50) {
        f32x4 s4 = *(const f32x4*)(sc + lane * 4);
        f32x4 b4 = *(const f32x4*)(bi + lane * 4);
        short4 o4;
        #pragma unroll
        for (int r = 0; r < 4; ++r)
            ((short*)&o4)[r] = f2b((v[r] - mean) * rstd * s4[r] + b4[r]);
        *(short4*)(o + lane * 4) = o4;
    } else if (lane < 56) {
        short4 z = {0, 0, 0, 0};
        *(short4*)(o + lane * 4) = z;
    }
}

// ---------------- bias precompute (ALL layers), split q-halves fragment order --------
__global__ void bias_pre4_k(const float* __restrict__ tabs, short* __restrict__ bp) {
    int l = blockIdx.y;
    int tid = blockIdx.x * 256 + threadIdx.x;
    const float* tab = tabs + (size_t)l * NRDz * Hz;
    int lane = tid & 63;
    int mi = (tid >> 6) & 1;
    int w  = (tid >> 7) & 3;
    int qb = (tid >> 9) & 1;
    int nj = (tid >> 10) & 3;
    int kc = (tid >> 12) & 3;
    int h  = tid >> 14;
    int q  = qb * 128 + w * 32 + mi * 16 + (lane & 15);
    int k0 = kc * 64 + nj * 16 + 4 * (lane >> 4);
    short4 o;
    #pragma unroll
    for (int r = 0; r < 4; ++r) {
        int k = k0 + r;
        float v;
        if (q > Nz || k > Nz) v = -1e30f;
        else if (k == 0)      v = (q == 0) ? tab[481 * Hz + h] : tab[480 * Hz + h];
        else if (q == 0)      v = tab[479 * Hz + h];
        else                  v = tab[(q - k + 239) * Hz + h];
        ((short*)&o)[r] = f2b(v * LOG2E);
    }
    *(short4*)(bp + (size_t)l * BIASL + (size_t)tid * 4) = o;
}

// ---------------- MFMA GEMM v8 (unchanged) ----------
template <int MODE, int BN2, int BM2>
__global__ __launch_bounds__(256) void gemm8_k(
        const short* __restrict__ A, const short* __restrict__ W,
        const float* __restrict__ bias, const float* __restrict__ bias2,
        const float* __restrict__ res, void* __restrict__ outv,
        short* __restrict__ qo, short* __restrict__ ko, short* __restrict__ vo,
        int M, int Nreal, int K, int strideA, int ldo, int gridx, int gridy) {
    constexpr int NJ = BN2 / 32;
    constexpr int MI = BM2 / 32;
    constexpr int AISS = BM2 / 64;
    constexpr int BISS = BN2 / 64;
    constexpr int LPS = AISS + BISS;
    __shared__ short smem[3 * (BM2 + BN2) * 32];
    short* Asb = smem;
    short* Bsb = smem + 3 * BM2 * 32;
    const int t = threadIdx.x;
    const int lane = t & 63, w = t >> 6;
    const int l15 = lane & 15, lg = lane >> 4;
    const int wm = w & 1, wn = w >> 1;

    int bx, by;
    {
        int wg = blockIdx.x;
        if ((gridy & 7) == 0) {
            int xcd = wg & 7, j = wg >> 3;
            bx = j % gridx;
            by = (j / gridx) * 8 + xcd;
        } else {
            bx = wg % gridx;
            by = wg / gridx;
        }
    }
    const int row0 = by * BM2, col0 = bx * BN2;
    const int xsw = (l15 >> 1) & 3;

    f32x4 acc[MI][NJ];
    #pragma unroll
    for (int mi = 0; mi < MI; ++mi)
        #pragma unroll
        for (int nj = 0; nj < NJ; ++nj) {
            f32x4 z = {0.f, 0.f, 0.f, 0.f};
            acc[mi][nj] = z;
        }

    const int nk = K >> 5;

    auto stage = [&](int buf, int kt) {
        const int k0 = kt * 32;
        #pragma unroll
        for (int i = 0; i < AISS; ++i) {
            int c = (w * AISS + i) * 64 + lane;
            int r = c >> 2, q = c & 3;
            const short* gp = A + (size_t)(row0 + r) * strideA + k0 + ((q ^ ((r >> 1) & 3)) * 8);
            gll16(gp, Asb + buf * BM2 * 32 + (w * AISS + i) * 512);
        }
        #pragma unroll
        for (int i = 0; i < BISS; ++i) {
            int c = (w * BISS + i) * 64 + lane;
            int r = c >> 2, q = c & 3;
            const short* gp = W + (size_t)(col0 + r) * K + k0 + ((q ^ ((r >> 1) & 3)) * 8);
            gll16(gp, Bsb + buf * BN2 * 32 + (w * BISS + i) * 512);
        }
    };

    stage(0, 0);
    if (nk > 1) stage(1, 1);
    for (int kt = 0; kt < nk; ++kt) {
        const int cur = kt % 3;
        if (kt + 1 < nk) wait_vm<LPS>();
        else             wait_vm<0>();
        __builtin_amdgcn_s_barrier();
        if (kt + 2 < nk) stage((kt + 2) % 3, kt + 2);
        bf16x8 bfr[NJ], afr[MI];
        #pragma unroll
        for (int nj = 0; nj < NJ; ++nj)
            bfr[nj] = *(const bf16x8*)(Bsb + cur * BN2 * 32 + (wn * (BN2 / 2) + nj * 16 + l15) * 32 + ((lg ^ xsw) * 8));
        #pragma unroll
        for (int mi = 0; mi < MI; ++mi)
            afr[mi] = *(const bf16x8*)(Asb + cur * BM2 * 32 + (wm * (BM2 / 2) + mi * 16 + l15) * 32 + ((lg ^ xsw) * 8));
        #pragma unroll
        for (int mi = 0; mi < MI; ++mi)
            #pragma unroll
            for (int nj = 0; nj < NJ; ++nj) {
                if (MODE == 1)
                    acc[mi][nj] = __builtin_amdgcn_mfma_f32_16x16x32_bf16(bfr[nj], afr[mi], acc[mi][nj], 0, 0, 0);
                else
                    acc[mi][nj] = __builtin_amdgcn_mfma_f32_16x16x32_bf16(afr[mi], bfr[nj], acc[mi][nj], 0, 0, 0);
            }
    }

    if (MODE == 1) {
        #pragma unroll
        for (int mi = 0; mi < MI; ++mi) {
            int m = row0 + wm * (BM2 / 2) + mi * 16 + l15;
            int b = m >> 8, s = m & 255;
            #pragma unroll
            for (int nj = 0; nj < NJ; ++nj) {
                int n0 = col0 + wn * (BN2 / 2) + nj * 16 + 4 * lg;
                if (n0 >= 600) continue;
                int which = n0 >= 400 ? 2 : (n0 >= 200 ? 1 : 0);
                int hd = n0 - which * 200;
                int h = hd / 20, d0 = hd - h * 20;
                size_t base = (size_t)(b * Hz + h) * 8192;
                if (which == 0) {
                    f32x4 qb4 = *(const f32x4*)(bias + hd);
                    short4 o4;
                    #pragma unroll
                    for (int r = 0; r < 4; ++r)
                        ((short*)&o4)[r] = f2b((acc[mi][nj][r] + qb4[r]) * SCALE2f);
                    *(short4*)(qo + base + s * 32 + d0) = o4;
                } else if (which == 1) {
                    int oct = (d0 >> 3) ^ ((s >> 1) & 3);
                    short4 o4;
                    #pragma unroll
                    for (int r = 0; r < 4; ++r)
                        ((short*)&o4)[r] = f2b(acc[mi][nj][r]);
                    *(short4*)(ko + base + s * 32 + oct * 8 + (d0 & 7)) = o4;
                } else {
                    f32x4 vb4 = *(const f32x4*)(bias2 + hd);
                    #pragma unroll
                    for (int r = 0; r < 4; ++r) {
                        int d = d0 + r;
                        vo[base + d * 256 + (s ^ ((d & 7) << 3))] = f2b(acc[mi][nj][r] + vb4[r]);
                    }
                }
            }
        }
        return;
    }

    if (MODE == 2 || MODE == 3) {
        __syncthreads();
        if (MODE == 3) {
            constexpr int EW = BN2 + 8;
            short* ep = smem;
            #pragma unroll
            for (int mi = 0; mi < MI; ++mi)
                #pragma unroll
                for (int nj = 0; nj < NJ; ++nj) {
                    int nl = wn * (BN2 / 2) + nj * 16 + l15;
                    int n = col0 + nl;
                    float bv = (n < Nreal) ? bias[n] : 0.f;
                    #pragma unroll
                    for (int r = 0; r < 4; ++r)
                        ep[(wm * (BM2 / 2) + mi * 16 + 4 * lg + r) * EW + nl] =
                            f2b(gelu_f(acc[mi][nj][r] + bv));
                }
            __syncthreads();
            constexpr int TPR = BN2 / 8;
            constexpr int RPP = 256 / TPR;
            int rowp = t / TPR, cch = t % TPR;
            #pragma unroll
            for (int p = 0; p < BM2 / RPP; ++p) {
                int row = p * RPP + rowp;
                int n = col0 + cch * 8;
                if (n + 8 <= Nreal)
                    *(bf16x8*)((short*)outv + (size_t)(row0 + row) * ldo + n) =
                        *(const bf16x8*)(ep + row * EW + cch * 8);
            }
        } else {
            constexpr int EWF = BN2 + 4;
            float* epf = (float*)smem;
            #pragma unroll
            for (int mi = 0; mi < MI; ++mi)
                #pragma unroll
                for (int nj = 0; nj < NJ; ++nj) {
                    int nl = wn * (BN2 / 2) + nj * 16 + l15;
                    int n = col0 + nl;
                    float bv = (n < Nreal) ? bias[n] : 0.f;
                    #pragma unroll
                    for (int r = 0; r < 4; ++r)
                        epf[(wm * (BM2 / 2) + mi * 16 + 4 * lg + r) * EWF + nl] =
                            acc[mi][nj][r] + bv;
                }
            __syncthreads();
            constexpr int TPR = BN2 / 4;
            constexpr int RPP = 256 / TPR;
            int rowp = t / TPR, cch = t % TPR;
            #pragma unroll
            for (int p = 0; p < BM2 / RPP; ++p) {
                int row = p * RPP + rowp;
                int n = col0 + cch * 4;
                if (n + 4 <= Nreal) {
                    size_t off = (size_t)(row0 + row) * ldo + n;
                    f32x4 v = *(const f32x4*)(epf + row * EWF + cch * 4);
                    f32x4 rr = *(const f32x4*)(res + off);
                    *(f32x4*)((float*)outv + off) = v + rr;
                }
            }
        }
        return;
    }

    #pragma unroll
    for (int mi = 0; mi < MI; ++mi) {
        #pragma unroll
        for (int nj = 0; nj < NJ; ++nj) {
            int n = col0 + wn * (BN2 / 2) + nj * 16 + l15;
            if (n >= Nreal) continue;
            if (MODE == 4) {
                #pragma unroll
                for (int r = 0; r < 4; ++r) {
                    int m = row0 + wm * (BM2 / 2) + mi * 16 + 4 * lg + r;
                    int bb = m / Nz, j = m - bb * Nz;
                    size_t trow = (size_t)bb * Sp + j + 1;
                    ((float*)outv)[trow * ldo + n] =
                        acc[mi][nj][r] + bias[n] + res[(size_t)(j + 1) * Dz + n];
                }
            } else {
                #pragma unroll
                for (int r = 0; r < 4; ++r) {
                    int m = row0 + wm * (BM2 / 2) + mi * 16 + 4 * lg + r;
                    if (m >= M) continue;
                    size_t off = (size_t)m * ldo + n;
                    ((float*)outv)[off] = acc[mi][nj][r] + bias[n];
                }
            }
        }
    }
}

// ---------------- MFMA attention v5b: mrow=0 init (fast path on kc=0) ----------
#define PLD 72
__global__ __launch_bounds__(256) void attn5_k(const short* __restrict__ Qb,
                                               const short* __restrict__ Kb,
                                               const short* __restrict__ Vtb,
                                               const short* __restrict__ biasC,
                                               short* __restrict__ o) {
    const int blk = blockIdx.x;
    const int qb = blk & 1;
    const int bh = blk >> 1;
    const int b = bh / Hz, h = bh - b * Hz;
    __shared__ short Ks[8192];
    __shared__ short Vt[8192];
    __shared__ short Pl[4][32 * PLD];
    const int t = threadIdx.x;
    const int lane = t & 63, w = t >> 6;
    const int l15 = lane & 15, lg = lane >> 4;

    const short* kbh = Kb + (size_t)bh * 8192;
    const short* vbh = Vtb + (size_t)bh * 8192;
    #pragma unroll
    for (int i = 0; i < 4; ++i) {
        int j = w * 4 + i;
        gll16(kbh + (size_t)(j * 64 + lane) * 8, Ks + j * 512);
        gll16(vbh + (size_t)(j * 64 + lane) * 8, Vt + j * 512);
    }
    bf16x8 qfrag[2];
    const short* qbh = Qb + (size_t)bh * 8192;
    #pragma unroll
    for (int mi = 0; mi < 2; ++mi) {
        int qrow = qb * 128 + w * 32 + mi * 16 + l15;
        qfrag[mi] = *(const bf16x8*)(qbh + qrow * 32 + lg * 8);
    }
    const short* bpp = biasC + 4 * (size_t)(lane + 128 * w + 512 * qb + 16384 * h);
    __syncthreads();

    f32x4 O[2][2];
    // mrow=0: fast path valid on kc=0 too (guard __all(s<=8) bounds P by 2^8;
    // rows whose true max < 0 just carry smaller P — ratio O/lrow unchanged).
    float mrow[2] = {0.f, 0.f};
    float lrow[2] = {0.f, 0.f};
    {
        f32x4 z = {0.f, 0.f, 0.f, 0.f};
        O[0][0] = z; O[0][1] = z; O[1][0] = z; O[1][1] = z;
    }
    const int xsw = (l15 >> 1) & 3;

    #pragma unroll 1
    for (int kc = 0; kc < 4; ++kc) {
        bf16x8 kf[4];
        #pragma unroll
        for (int nj = 0; nj < 4; ++nj)
            kf[nj] = *(const bf16x8*)(Ks + (kc * 64 + nj * 16 + l15) * 32 + ((lg ^ xsw) * 8));
        f32x4 s[2][4];
        __builtin_amdgcn_s_setprio(1);
        #pragma unroll
        for (int mi = 0; mi < 2; ++mi)
            #pragma unroll
            for (int nj = 0; nj < 4; ++nj) {
                f32x4 z = {0.f, 0.f, 0.f, 0.f};
                s[mi][nj] = __builtin_amdgcn_mfma_f32_16x16x32_bf16(kf[nj], qfrag[mi], z, 0, 0, 0);
            }
        __builtin_amdgcn_s_setprio(0);
        const short* bkc = bpp + kc * 16384;
        #pragma unroll
        for (int mi = 0; mi < 2; ++mi)
            #pragma unroll
            for (int nj = 0; nj < 4; ++nj) {
                short4 bp4 = *(const short4*)(bkc + nj * 4096 + mi * 256);
                s[mi][nj][0] += b2f(bp4.x);
                s[mi][nj][1] += b2f(bp4.y);
                s[mi][nj][2] += b2f(bp4.z);
                s[mi][nj][3] += b2f(bp4.w);
            }
        #pragma unroll
        for (int mi = 0; mi < 2; ++mi) {
            float mx = s[mi][0][0];
            #pragma unroll
            for (int nj = 0; nj < 4; ++nj)
                #pragma unroll
                for (int c = 0; c < 4; ++c) mx = fmaxf(mx, s[mi][nj][c]);
            mx = fmaxf(mx, __shfl_xor(mx, 16));
            mx = fmaxf(mx, __shfl_xor(mx, 32));
            float ssum = 0.f;
            if (__all(mx - mrow[mi] <= 8.f)) {
                float mn = mrow[mi];
                #pragma unroll
                for (int nj = 0; nj < 4; ++nj)
                    #pragma unroll
                    for (int c = 0; c < 4; ++c) {
                        float p = exp2f(s[mi][nj][c] - mn);
                        s[mi][nj][c] = p;
                        ssum += p;
                    }
                ssum += __shfl_xor(ssum, 16);
                ssum += __shfl_xor(ssum, 32);
                lrow[mi] += ssum;
            } else {
                float mn = fmaxf(mrow[mi], mx);
                float scn = exp2f(mrow[mi] - mn);
                mrow[mi] = mn;
                #pragma unroll
                for (int nj = 0; nj < 4; ++nj)
                    #pragma unroll
                    for (int c = 0; c < 4; ++c) {
                        float p = exp2f(s[mi][nj][c] - mn);
                        s[mi][nj][c] = p;
                        ssum += p;
                    }
                ssum += __shfl_xor(ssum, 16);
                ssum += __shfl_xor(ssum, 32);
                lrow[mi] = lrow[mi] * scn + ssum;
                f32x4 scd;
                #pragma unroll
                for (int r = 0; r < 4; ++r) scd[r] = __shfl(scn, 4 * lg + r);
                O[mi][0] *= scd;
                O[mi][1] *= scd;
            }
            #pragma unroll
            for (int nj = 0; nj < 4; ++nj)
                *(uint2*)(Pl[w] + (mi * 16 + l15) * PLD + nj * 16 + 4 * lg) =
                    pk4(s[mi][nj][0], s[mi][nj][1], s[mi][nj][2], s[mi][nj][3]);
        }
        #pragma unroll
        for (int kk = 0; kk < 2; ++kk) {
            bf16x8 vf[2];
            #pragma unroll
            for (int dj = 0; dj < 2; ++dj) {
                int d = dj * 16 + l15;
                int cb = (kc * 128 + kk * 64 + lg * 16) ^ ((l15 & 7) << 4);
                vf[dj] = *(const bf16x8*)((const char*)Vt + d * 512 + cb);
            }
            __builtin_amdgcn_s_setprio(1);
            #pragma unroll
            for (int mi = 0; mi < 2; ++mi) {
                bf16x8 af = *(const bf16x8*)(Pl[w] + (mi * 16 + l15) * PLD + kk * 32 + lg * 8);
                O[mi][0] = __builtin_amdgcn_mfma_f32_16x16x32_bf16(af, vf[0], O[mi][0], 0, 0, 0);
                O[mi][1] = __builtin_amdgcn_mfma_f32_16x16x32_bf16(af, vf[1], O[mi][1], 0, 0, 0);
            }
            __builtin_amdgcn_s_setprio(0);
        }
    }

    #pragma unroll
    for (int mi = 0; mi < 2; ++mi) {
        float linv = 1.f / lrow[mi];
        f32x4 invd;
        #pragma unroll
        for (int r = 0; r < 4; ++r) invd[r] = __shfl(linv, 4 * lg + r);
        #pragma unroll
        for (int dj = 0; dj < 2; ++dj) {
            int d = dj * 16 + l15;
            if (d >= HDz) continue;
            #pragma unroll
            for (int r = 0; r < 4; ++r) {
                int q = qb * 128 + w * 32 + mi * 16 + 4 * lg + r;
                if (q < Sz)
                    o[((size_t)b * Sp + q) * Kp + h * HDz + d] = f2b(O[mi][dj][r] * invd[r]);
            }
        }
    }
}

// ---------------- pool + fc_norm -> bf16 pooled ----------------
__global__ void pool_norm_k(const float* __restrict__ tok, const float* __restrict__ sc,
                            const float* __restrict__ bi, short* __restrict__ pooled) {
    int b = blockIdx.x;
    int t = threadIdx.x;
    float val = 0.f;
    if (t < Dz) {
        const float* base = tok + ((size_t)b * Sp + 1) * Dz + t;
        float s = 0.f;
        for (int si = 0; si < Nz; ++si) s += base[(size_t)si * Dz];
        val = s * (1.f / Nz);
    }
    __shared__ float red[8];
    float sum = val, sq = val * val;
    #pragma unroll
    for (int off = 32; off; off >>= 1) { sum += __shfl_xor(sum, off); sq += __shfl_xor(sq, off); }
    int wave = t >> 6, lane = t & 63;
    if (lane == 0) { red[wave] = sum; red[4 + wave] = sq; }
    __syncthreads();
    sum = red[0] + red[1] + red[2] + red[3];
    sq = red[4] + red[5] + red[6] + red[7];
    float mean = sum * (1.f / Dz);
    float var = sq * (1.f / Dz) - mean * mean;
    float rstd = rsqrtf(var + 1e-6f);
    if (t < Dz) pooled[(size_t)b * Kp + t] = f2b((val - mean) * rstd * sc[t] + bi[t]);
    else if (t < Kp) pooled[(size_t)b * Kp + t] = 0;
}

extern "C" void kernel_launch(void* const* d_in, const int* in_sizes, int n_in,
                              void* d_out, int out_size, void* d_ws, size_t ws_size,
                              hipStream_t stream) {
    const float* x        = (const float*)d_in[0];
    const float* conv_w   = (const float*)d_in[1];
    const float* conv_b   = (const float*)d_in[2];
    const float* cls_tok  = (const float*)d_in[3];
    const float* pos_emb  = (const float*)d_in[4];
    const float* ln1_s    = (const float*)d_in[5];
    const float* ln1_b    = (const float*)d_in[6];
    const float* qkv_w    = (const float*)d_in[7];
    const float* q_bias   = (const float*)d_in[8];
    const float* v_bias   = (const float*)d_in[9];
    const float* rpb      = (const float*)d_in[10];
    const float* proj_w   = (const float*)d_in[11];
    const float* proj_b   = (const float*)d_in[12];
    const float* ln2_s    = (const float*)d_in[13];
    const float* ln2_b    = (const float*)d_in[14];
    const float* fc1_w    = (const float*)d_in[15];
    const float* fc1_b    = (const float*)d_in[16];
    const float* fc2_w    = (const float*)d_in[17];
    const float* fc2_b    = (const float*)d_in[18];
    const float* fcn_s    = (const float*)d_in[19];
    const float* fcn_b    = (const float*)d_in[20];
    const float* head_w   = (const float*)d_in[21];
    const float* head_b   = (const float*)d_in[22];
    float* out = (float*)d_out;

    char* ws = (char*)d_ws;
    float* tok  = (float*)ws;  ws += (size_t)Mp * Dz * 4;
    short* xa   = (short*)ws;  ws += (size_t)Mp * Kp * 2;
    short* xb   = (short*)ws;  ws += (size_t)Mp * Kp * 2;
    short* xc   = (short*)ws;  ws += (size_t)Mp * Kp * 2;
    short* mid  = (short*)ws;  ws += (size_t)Mp * FFz * 2;
    short* Qb   = (short*)ws;  ws += (size_t)640 * 8192 * 2;
    short* Kb   = (short*)ws;  ws += (size_t)640 * 8192 * 2;
    short* Vtb  = (short*)ws;  ws += (size_t)640 * 8192 * 2;
    short* wq = (short*)ws;    ws += (size_t)Lz * 640 * Kp * 2;
    short* wp = (short*)ws;    ws += (size_t)Lz * 256 * Kp * 2;
    short* w1 = (short*)ws;    ws += (size_t)Lz * 896 * Kp * 2;
    short* w2 = (short*)ws;    ws += (size_t)Lz * 256 * FFz * 2;
    short* wh = (short*)ws;    ws += (size_t)1024 * Kp * 2;
    short* biasC = (short*)ws; ws += (size_t)Lz * BIASL * 2;
    short* xpb  = (short*)ws;  ws += (size_t)PEM * 64 * 2;
    short* wpe  = (short*)ws;  ws += (size_t)256 * 64 * 2;
    short* pooledb = (short*)ws; ws += (size_t)128 * Kp * 2;

    // xa pad rows feed K/V values -> must stay finite zeros (NaN would poison softmax).
    // pooledb rows 64..127 feed only discarded MFMA output rows (0xAA bf16 is finite).
    hipMemsetAsync(xa, 0, (size_t)Mp * Kp * 2, stream);

    cvt_all_k<<<(SEG5 + 255) / 256, 256, 0, stream>>>(
        qkv_w, proj_w, fc1_w, fc2_w, head_w, conv_w, wq, wpe);
    bias_pre4_k<<<dim3(640, Lz), 256, 0, stream>>>(rpb, biasC);

    xcvt_k<<<(PEM * 64) / 256, 256, 0, stream>>>(x, xpb);
    gemm8_k<4, 64, 128><<<4 * (PEM / 128), 256, 0, stream>>>(
        xpb, wpe, conv_b, nullptr, pos_emb, tok,
        nullptr, nullptr, nullptr, PEM, Dz, 64, 64, Dz, 4, PEM / 128);
    cls_k<<<Bz, 256, 0, stream>>>(cls_tok, pos_emb, tok);

    dim3 blk(256);
    ln_k<<<Mp / 4, blk, 0, stream>>>(tok, xa, ln1_s, ln1_b);
    for (int l = 0; l < Lz; ++l) {
        gemm8_k<1, 128, 64><<<5 * (Mp / 64), blk, 0, stream>>>(
            xa, wq + (size_t)l * 640 * Kp, q_bias + l * Dz, v_bias + l * Dz,
            nullptr, nullptr, Qb, Kb, Vtb,
            Mp, 600, Kp, Kp, 0, 5, Mp / 64);
        attn5_k<<<1280, blk, 0, stream>>>(Qb, Kb, Vtb, biasC + (size_t)l * BIASL, xb);
        gemm8_k<2, 64, 64><<<4 * (Mp / 64), blk, 0, stream>>>(
            xb, wp + (size_t)l * 256 * Kp, proj_b + l * Dz, nullptr,
            tok, tok, nullptr, nullptr, nullptr,
            Mp, Dz, Kp, Kp, Dz, 4, Mp / 64);
        ln_k<<<Mp / 4, blk, 0, stream>>>(tok, xc, ln2_s + l * Dz, ln2_b + l * Dz);
        gemm8_k<3, 128, 64><<<7 * (Mp / 64), blk, 0, stream>>>(
            xc, w1 + (size_t)l * 896 * Kp, fc1_b + l * FFz, nullptr,
            nullptr, mid, nullptr, nullptr, nullptr,
            Mp, FFz, Kp, Kp, FFz, 7, Mp / 64);
        gemm8_k<2, 64, 64><<<4 * (Mp / 64), blk, 0, stream>>>(
            mid, w2 + (size_t)l * 256 * FFz, fc2_b + l * Dz, nullptr,
            tok, tok, nullptr, nullptr, nullptr,
            Mp, Dz, FFz, FFz, Dz, 4, Mp / 64);
        if (l + 1 < Lz)   // final iteration's ln1 output is never consumed
            ln_k<<<Mp / 4, blk, 0, stream>>>(tok, xa, ln1_s + (size_t)(l + 1) * Dz,
                                             ln1_b + (size_t)(l + 1) * Dz);
    }

    pool_norm_k<<<Bz, blk, 0, stream>>>(tok, fcn_s, fcn_b, pooledb);
    gemm8_k<0, 128, 128><<<8, blk, 0, stream>>>(
        pooledb, wh, head_b, nullptr, nullptr, out,
        nullptr, nullptr, nullptr, Bz, NCz, Kp, Kp, NCz, 8, 1);
}